// Round 2
// baseline (790.697 us; speedup 1.0000x reference)
//
#include <hip/hip_runtime.h>
#include <hip/hip_bf16.h>
#include <cstdint>

// Problem constants: B=64, T=512, E=256, H=128, 4H=512.
#define BB 64
#define TT 512
#define EE 256
#define HH 128
#define G4 512

typedef _Float16 half2_t __attribute__((ext_vector_type(2)));
typedef _Float16 f16x4 __attribute__((ext_vector_type(4)));
typedef _Float16 f16x8 __attribute__((ext_vector_type(8)));
typedef float f32x4 __attribute__((ext_vector_type(4)));

__device__ __forceinline__ float fdot2f(half2_t a, half2_t b, float c) {
#if defined(__has_builtin)
#if __has_builtin(__builtin_amdgcn_fdot2)
  return __builtin_amdgcn_fdot2(a, b, c, false);
#else
  return c + (float)a[0] * (float)b[0] + (float)a[1] * (float)b[1];
#endif
#else
  return c + (float)a[0] * (float)b[0] + (float)a[1] * (float)b[1];
#endif
}

__device__ __forceinline__ half2_t bc16(float x) { return __builtin_bit_cast(half2_t, x); }
__device__ __forceinline__ float rcp_(float x) { return __builtin_amdgcn_rcpf(x); }
__device__ __forceinline__ float sigmoid_(float x) {
  return rcp_(1.f + __expf(-x));
}
__device__ __forceinline__ float tanh_(float x) {
  float ax = fabsf(x);
  float e = __expf(-2.f * ax);  // in (0,1], no overflow ever
  float r = (1.f - e) * rcp_(1.f + e);
  return copysignf(r, x);
}

// ---------------------------------------------------------------------------
// Kernel A: trans = row-softmax(transition); W16 = (f16)W_ih
// ---------------------------------------------------------------------------
__global__ __launch_bounds__(128) void prep_kernel(
    const float* __restrict__ transition, const float* __restrict__ W_ih,
    float* __restrict__ trans, _Float16* __restrict__ W16) {
  const int bid = blockIdx.x, t = threadIdx.x;
  if (bid < 128) {
    __shared__ float red[2];
    float v = transition[bid * HH + t];
    float m = v;
#pragma unroll
    for (int s = 32; s >= 1; s >>= 1) m = fmaxf(m, __shfl_xor(m, s));
    if ((t & 63) == 0) red[t >> 6] = m;
    __syncthreads();
    m = fmaxf(red[0], red[1]);
    float e = __expf(v - m);
    float s = e;
#pragma unroll
    for (int k = 32; k >= 1; k >>= 1) s += __shfl_xor(s, k);
    __syncthreads();
    if ((t & 63) == 0) red[t >> 6] = s;
    __syncthreads();
    trans[bid * HH + t] = e * rcp_(red[0] + red[1]);
  } else {
    const int base = (bid - 128) * 1024 + t * 8;
    float4 v0 = *(const float4*)(W_ih + base);
    float4 v1 = *(const float4*)(W_ih + base + 4);
    f16x8 h;
    h[0] = (_Float16)v0.x; h[1] = (_Float16)v0.y;
    h[2] = (_Float16)v0.z; h[3] = (_Float16)v0.w;
    h[4] = (_Float16)v1.x; h[5] = (_Float16)v1.y;
    h[6] = (_Float16)v1.z; h[7] = (_Float16)v1.w;
    *(f16x8*)(W16 + base) = h;
  }
}

// ---------------------------------------------------------------------------
// Kernel B: precomp[m][j] = inputs@W_ih^T + b_ih + b_hh (f16 MFMA 16x16x32)
// ---------------------------------------------------------------------------
__global__ __launch_bounds__(256) void gemm_in(
    const float* __restrict__ A, const _Float16* __restrict__ W16,
    const float* __restrict__ b_ih, const float* __restrict__ b_hh,
    float* __restrict__ out) {
  __shared__ _Float16 As[64][264];
  const int t = threadIdx.x;
  const int m0 = blockIdx.x * 64;
  const int n0 = blockIdx.y * 256;
  {
    const int c4 = t & 63, r0 = t >> 6;
#pragma unroll
    for (int p = 0; p < 16; ++p) {
      const int row = r0 + 4 * p;
      float4 v = *(const float4*)(A + (size_t)(m0 + row) * EE + c4 * 4);
      f16x4 h;
      h[0] = (_Float16)v.x; h[1] = (_Float16)v.y;
      h[2] = (_Float16)v.z; h[3] = (_Float16)v.w;
      *(f16x4*)&As[row][c4 * 4] = h;
    }
  }
  __syncthreads();
  const int w = t >> 6, L = t & 63;
  const int lrow = L & 15, quad = L >> 4, lk = quad * 8;
  f32x4 acc[4][4] = {};
  const _Float16* Wbase = W16 + (size_t)(n0 + w * 64) * EE;
#pragma unroll
  for (int kc = 0; kc < 8; ++kc) {
    f16x8 a[4], bf[4];
#pragma unroll
    for (int mf = 0; mf < 4; ++mf)
      a[mf] = *(const f16x8*)&As[mf * 16 + lrow][kc * 32 + lk];
#pragma unroll
    for (int nf = 0; nf < 4; ++nf)
      bf[nf] = *(const f16x8*)(Wbase + (size_t)(nf * 16 + lrow) * EE + kc * 32 + lk);
#pragma unroll
    for (int mf = 0; mf < 4; ++mf)
#pragma unroll
      for (int nf = 0; nf < 4; ++nf)
        acc[mf][nf] = __builtin_amdgcn_mfma_f32_16x16x32_f16(a[mf], bf[nf], acc[mf][nf], 0, 0, 0);
  }
#pragma unroll
  for (int nf = 0; nf < 4; ++nf) {
    const int jj = n0 + w * 64 + nf * 16 + lrow;
    const float bias = b_ih[jj] + b_hh[jj];
#pragma unroll
    for (int mf = 0; mf < 4; ++mf) {
#pragma unroll
      for (int r = 0; r < 4; ++r) {
        const int m = m0 + mf * 16 + quad * 4 + r;
        out[(size_t)m * G4 + jj] = acc[mf][nf][r] + bias;
      }
    }
  }
}

// ---------------------------------------------------------------------------
// Kernel C: fused LSTM + softmax + CRF forward.  One block (512 thr) / batch.
// Thread t -> unit j = t>>2 (owns gate rows j,j+128,j+256,j+384 AND CRF col j),
// K-chunk k = t&3 (32 elements).  Cross-chunk reduce via shfl_xor(1,2).
// CRF pipeline lags LSTM by one iteration; ONE barrier per step, all state
// double-buffered (h16/E16/redE/pre0).
// ---------------------------------------------------------------------------
__global__ __launch_bounds__(512, 2) void lstm_crf(
    const float* __restrict__ precomp, const float* __restrict__ Whh,
    const float* __restrict__ trans, const int* __restrict__ labels,
    float* __restrict__ out_b) {
  const int b = blockIdx.x, t = threadIdx.x;
  const int k = t & 3, j = t >> 2;   // j in [0,128)
  const int w = t >> 6;              // wave 0..7
  __shared__ __align__(16) _Float16 h16[2][HH];
  __shared__ __align__(16) _Float16 E16[2][HH];
  __shared__ __align__(16) float redE[2][8];
  __shared__ float pre0[2];
  __shared__ float fin[24];
  __shared__ int lab[TT];

  // ---- one-time register loads -------------------------------------------
  half2_t wreg[4][16];  // W_hh[j+128g][32k + 2m (+1)]
#pragma unroll
  for (int g = 0; g < 4; ++g) {
    const float4* wr = (const float4*)(Whh + (size_t)(j + 128 * g) * HH + 32 * k);
#pragma unroll
    for (int p = 0; p < 8; ++p) {
      float4 v = wr[p];
      half2_t a, c2;
      a[0] = (_Float16)v.x; a[1] = (_Float16)v.y;
      c2[0] = (_Float16)v.z; c2[1] = (_Float16)v.w;
      wreg[g][2 * p] = a; wreg[g][2 * p + 1] = c2;
    }
  }
  half2_t et[16];  // exp(trans[32k+2m (+1)][j])
#pragma unroll
  for (int m = 0; m < 16; ++m) {
    float e0 = __expf(trans[(32 * k + 2 * m) * HH + j]);
    float e1 = __expf(trans[(32 * k + 2 * m + 1) * HH + j]);
    half2_t hh; hh[0] = (_Float16)e0; hh[1] = (_Float16)e1;
    et[m] = hh;
  }
  const float tr0 = trans[j];
  const float tr127 = trans[127 * HH + j];
  lab[t] = labels[b * TT + t];
  if (t < HH) {
    h16[0][t] = (_Float16)0.f; h16[1][t] = (_Float16)0.f;
    E16[0][t] = (_Float16)0.f; E16[1][t] = (_Float16)0.f;
  }
  if (t < 16) redE[t >> 3][t & 7] = 0.f;
  float c = 0.f, pre = 0.f, mused = 0.f, emitacc = 0.f, e_prev = 0.f;
  const float* pc = precomp + (size_t)b * TT * G4 + j + 128 * k;
  float nxt = pc[0];
  __syncthreads();

#pragma unroll 1
  for (int n = 0; n <= TT; ++n) {
    // ---- LDS reads of previous-iteration state (all RAW across 1 barrier) -
    const float4* hb = (const float4*)(&h16[(n + 1) & 1][0]) + k * 4;  // h(n-1)
    const float4* eb = (const float4*)(&E16[n & 1][0]) + k * 4;        // E(n-2)
    float4 q0 = hb[0], q1 = hb[1], q2 = hb[2], q3 = hb[3];
    float4 u0 = eb[0], u1 = eb[1], u2 = eb[2], u3 = eb[3];
    float4 r0 = *(const float4*)&redE[(n + 1) & 1][0];                 // tot(n-1)
    float4 r1 = *(const float4*)&redE[(n + 1) & 1][4];
    float Mnew = pre0[(n + 1) & 1];                                    // pre_0(n-2)
    const float cur = nxt;
    if (n + 1 < TT) nxt = pc[(size_t)(n + 1) * G4];

    // ---- LSTM matvec over chunk k + gate reduce ---------------------------
    half2_t hx[16];
    hx[0] = bc16(q0.x); hx[1] = bc16(q0.y); hx[2] = bc16(q0.z); hx[3] = bc16(q0.w);
    hx[4] = bc16(q1.x); hx[5] = bc16(q1.y); hx[6] = bc16(q1.z); hx[7] = bc16(q1.w);
    hx[8] = bc16(q2.x); hx[9] = bc16(q2.y); hx[10] = bc16(q2.z); hx[11] = bc16(q2.w);
    hx[12] = bc16(q3.x); hx[13] = bc16(q3.y); hx[14] = bc16(q3.z); hx[15] = bc16(q3.w);
    float a0 = 0.f, a1 = 0.f, a2 = 0.f, a3 = 0.f;
#pragma unroll
    for (int m = 0; m < 16; ++m) {
      a0 = fdot2f(wreg[0][m], hx[m], a0);
      a1 = fdot2f(wreg[1][m], hx[m], a1);
      a2 = fdot2f(wreg[2][m], hx[m], a2);
      a3 = fdot2f(wreg[3][m], hx[m], a3);
    }
    a0 += (k == 0) ? cur : 0.f;
    a1 += (k == 1) ? cur : 0.f;
    a2 += (k == 2) ? cur : 0.f;
    a3 += (k == 3) ? cur : 0.f;
    a0 += __shfl_xor(a0, 1); a0 += __shfl_xor(a0, 2);
    a1 += __shfl_xor(a1, 1); a1 += __shfl_xor(a1, 2);
    a2 += __shfl_xor(a2, 1); a2 += __shfl_xor(a2, 2);
    a3 += __shfl_xor(a3, 1); a3 += __shfl_xor(a3, 2);

    // ---- CRF matvec: S_j(n-1) = sum_i E_i(n-2) * ET[i][j] -----------------
    half2_t ex[16];
    ex[0] = bc16(u0.x); ex[1] = bc16(u0.y); ex[2] = bc16(u0.z); ex[3] = bc16(u0.w);
    ex[4] = bc16(u1.x); ex[5] = bc16(u1.y); ex[6] = bc16(u1.z); ex[7] = bc16(u1.w);
    ex[8] = bc16(u2.x); ex[9] = bc16(u2.y); ex[10] = bc16(u2.z); ex[11] = bc16(u2.w);
    ex[12] = bc16(u3.x); ex[13] = bc16(u3.y); ex[14] = bc16(u3.z); ex[15] = bc16(u3.w);
    float s0 = 0.f;
#pragma unroll
    for (int m = 0; m < 16; ++m) s0 = fdot2f(et[m], ex[m], s0);
    s0 += __shfl_xor(s0, 1); s0 += __shfl_xor(s0, 2);

    // ---- LSTM cell update (all 4 lanes of group j, redundantly) -----------
    float e_cur = 0.f;
    if (n < TT) {
      const float iv = sigmoid_(a0), fv = sigmoid_(a1);
      const float gv = tanh_(a2), ov = sigmoid_(a3);
      c = fv * c + iv * gv;
      const float hval = ov * tanh_(c);
      e_cur = __expf(hval);  // |hval|<1
      float ts = e_cur;
#pragma unroll
      for (int d = 1; d <= 32; d <<= 1) ts += __shfl_xor(ts, d);
      if ((t & 63) == 0) redE[n & 1][w] = ts;  // 4 * sum_{j in wave} e_j
      if (k == 0) h16[n & 1][j] = (_Float16)hval;
    }

    // ---- CRF update for step m = n-1 --------------------------------------
    if (n > 0) {
      const float tot = r0.x + r0.y + r0.z + r0.w + r1.x + r1.y + r1.z + r1.w;
      const float p = e_prev * 4.f * rcp_(tot);  // softmax prob of unit j
      if (n == 1) { pre = p + tr0; Mnew = 0.f; }
      else pre = p + mused + __logf(s0);
      if (t == 0) pre0[n & 1] = pre;
      if (k == 0) E16[(n + 1) & 1][j] = (_Float16)__expf(pre - Mnew);
      mused = Mnew;
      if (k == 0 && lab[n - 1] == j) emitacc += p;
    }
    e_prev = e_cur;
    __syncthreads();
  }

  // ---- epilogue: Ps = LSE_j(pre + tr127); out_b = Ps - emit ---------------
  float v = pre + tr127;
  float mx = v;
#pragma unroll
  for (int d = 1; d <= 32; d <<= 1) mx = fmaxf(mx, __shfl_xor(mx, d));
  if ((t & 63) == 0) fin[w] = mx;
  __syncthreads();
  float M2 = fin[0];
#pragma unroll
  for (int i = 1; i < 8; ++i) M2 = fmaxf(M2, fin[i]);
  float ex2 = __expf(v - M2);
#pragma unroll
  for (int d = 1; d <= 32; d <<= 1) ex2 += __shfl_xor(ex2, d);
  float em = emitacc;
#pragma unroll
  for (int d = 1; d <= 32; d <<= 1) em += __shfl_xor(em, d);
  if ((t & 63) == 0) { fin[8 + w] = ex2; fin[16 + w] = em; }
  __syncthreads();
  if (t == 0) {
    float S = 0.f, E = 0.f;
#pragma unroll
    for (int i = 0; i < 8; ++i) { S += fin[8 + i]; E += fin[16 + i]; }
    const float Ps = M2 + __logf(S * 0.25f);
    out_b[b] = Ps - E;
  }
}

// ---------------------------------------------------------------------------
// Kernel D: total = sum_b out_b[b] - sum_{b,t<511} trans[l_t][l_{t+1}]
// ---------------------------------------------------------------------------
__global__ __launch_bounds__(512) void finalize_kernel(
    const float* __restrict__ trans, const int* __restrict__ labels,
    const float* __restrict__ out_b, float* __restrict__ d_out) {
  const int t = threadIdx.x;
  float a = 0.f;
  if (t < TT - 1) {
    for (int b = 0; b < BB; ++b) {
      const int l0 = labels[b * TT + t];
      const int l1 = labels[b * TT + t + 1];
      a += trans[l0 * HH + l1];
    }
  }
  float x = ((t < BB) ? out_b[t] : 0.f) - a;
  __shared__ float red[8];
#pragma unroll
  for (int s = 32; s >= 1; s >>= 1) x += __shfl_xor(x, s);
  if ((t & 63) == 0) red[t >> 6] = x;
  __syncthreads();
  if (t == 0) {
    float s = 0.f;
#pragma unroll
    for (int i = 0; i < 8; ++i) s += red[i];
    d_out[0] = s;
  }
}

// ---------------------------------------------------------------------------
extern "C" void kernel_launch(void* const* d_in, const int* in_sizes, int n_in,
                              void* d_out, int out_size, void* d_ws, size_t ws_size,
                              hipStream_t stream) {
  const float* inputs = (const float*)d_in[0];
  const int* labels = (const int*)d_in[1];
  const float* W_ih = (const float*)d_in[2];
  const float* W_hh = (const float*)d_in[3];
  const float* b_ih = (const float*)d_in[4];
  const float* b_hh = (const float*)d_in[5];
  const float* transition = (const float*)d_in[6];

  char* ws = (char*)d_ws;
  float* precomp = (float*)ws;                           // 64 MiB
  float* trans = (float*)(ws + 67108864);                // 64 KiB
  _Float16* W16 = (_Float16*)(ws + 67108864 + 65536);    // 256 KiB
  float* out_b = (float*)(ws + 67108864 + 65536 + 262144);

  prep_kernel<<<256, 128, 0, stream>>>(transition, W_ih, trans, W16);
  gemm_in<<<dim3(512, 2), 256, 0, stream>>>(inputs, W16, b_ih, b_hh, precomp);
  lstm_crf<<<64, 512, 0, stream>>>(precomp, W_hh, trans, labels, out_b);
  finalize_kernel<<<1, 512, 0, stream>>>(trans, labels, out_b, (float*)d_out);
}

// Round 4
// 701.511 us; speedup vs baseline: 1.1271x; 1.1271x over previous
//
#include <hip/hip_runtime.h>
#include <hip/hip_bf16.h>
#include <cstdint>

// Problem constants: B=64, T=512, E=256, H=128, 4H=512.
#define BB 64
#define TT 512
#define EE 256
#define HH 128
#define G4 512

typedef _Float16 f16x4 __attribute__((ext_vector_type(4)));
typedef _Float16 f16x8 __attribute__((ext_vector_type(8)));
typedef float f32x4 __attribute__((ext_vector_type(4)));

__device__ __forceinline__ float rcp_(float x) { return __builtin_amdgcn_rcpf(x); }
__device__ __forceinline__ float sigmoid_(float x) { return rcp_(1.f + __expf(-x)); }
__device__ __forceinline__ float tanh_(float x) {
  float ax = fabsf(x);
  float e = __expf(-2.f * ax);  // in (0,1], no overflow
  float r = (1.f - e) * rcp_(1.f + e);
  return copysignf(r, x);
}
// DPP-based wave reduction (VALU pipe, NOT the LDS pipe like __shfl).
template <int ctrl>
__device__ __forceinline__ float dpp_add(float x) {
  int y = __builtin_amdgcn_update_dpp(0, __builtin_bit_cast(int, x), ctrl, 0xf, 0xf, true);
  return x + __builtin_bit_cast(float, y);
}
__device__ __forceinline__ float wave_sum63(float x) {  // total lands in lane 63
  x = dpp_add<0x111>(x);  // row_shr:1
  x = dpp_add<0x112>(x);  // row_shr:2
  x = dpp_add<0x114>(x);  // row_shr:4
  x = dpp_add<0x118>(x);  // row_shr:8
  x = dpp_add<0x142>(x);  // row_bcast:15
  x = dpp_add<0x143>(x);  // row_bcast:31
  return x;
}
__device__ __forceinline__ float sel4(f32x4 v, int s) {  // v[s], s in [0,4)
  float a = (s & 1) ? v[1] : v[0];
  float b = (s & 1) ? v[3] : v[2];
  return (s & 2) ? b : a;
}

// ---------------------------------------------------------------------------
// Kernel A: trans = row-softmax(transition); W16 = (f16)W_ih; Whh16 = (f16)W_hh
// grid 320 x 128 threads.
// ---------------------------------------------------------------------------
__global__ __launch_bounds__(128) void prep_kernel(
    const float* __restrict__ transition, const float* __restrict__ W_ih,
    const float* __restrict__ W_hh, float* __restrict__ trans,
    _Float16* __restrict__ W16, _Float16* __restrict__ Whh16) {
  const int bid = blockIdx.x, t = threadIdx.x;
  if (bid < 128) {
    __shared__ float red[2];
    float v = transition[bid * HH + t];
    float m = v;
#pragma unroll
    for (int s = 32; s >= 1; s >>= 1) m = fmaxf(m, __shfl_xor(m, s));
    if ((t & 63) == 0) red[t >> 6] = m;
    __syncthreads();
    m = fmaxf(red[0], red[1]);
    float e = __expf(v - m);
    float s = e;
#pragma unroll
    for (int k = 32; k >= 1; k >>= 1) s += __shfl_xor(s, k);
    __syncthreads();
    if ((t & 63) == 0) red[t >> 6] = s;
    __syncthreads();
    trans[bid * HH + t] = e * rcp_(red[0] + red[1]);
  } else if (bid < 256) {
    const int base = (bid - 128) * 1024 + t * 8;  // 131072 elems of W_ih
    float4 v0 = *(const float4*)(W_ih + base);
    float4 v1 = *(const float4*)(W_ih + base + 4);
    f16x8 h;
    h[0] = (_Float16)v0.x; h[1] = (_Float16)v0.y;
    h[2] = (_Float16)v0.z; h[3] = (_Float16)v0.w;
    h[4] = (_Float16)v1.x; h[5] = (_Float16)v1.y;
    h[6] = (_Float16)v1.z; h[7] = (_Float16)v1.w;
    *(f16x8*)(W16 + base) = h;
  } else {
    const int base = (bid - 256) * 1024 + t * 8;  // 65536 elems of W_hh
    float4 v0 = *(const float4*)(W_hh + base);
    float4 v1 = *(const float4*)(W_hh + base + 4);
    f16x8 h;
    h[0] = (_Float16)v0.x; h[1] = (_Float16)v0.y;
    h[2] = (_Float16)v0.z; h[3] = (_Float16)v0.w;
    h[4] = (_Float16)v1.x; h[5] = (_Float16)v1.y;
    h[6] = (_Float16)v1.z; h[7] = (_Float16)v1.w;
    *(f16x8*)(Whh16 + base) = h;
  }
}

// ---------------------------------------------------------------------------
// Kernel A2: ETT[j][i] = (f16) exp(trans[i][j])  (transposed exp-transition)
// ---------------------------------------------------------------------------
__global__ __launch_bounds__(256) void prep2_kernel(
    const float* __restrict__ trans, _Float16* __restrict__ ETT) {
  const int idx = blockIdx.x * 256 + threadIdx.x;  // 16384 total
  const int j = idx >> 7, i = idx & 127;
  ETT[j * HH + i] = (_Float16)__expf(trans[i * HH + j]);
}

// ---------------------------------------------------------------------------
// Kernel B: precomp[m][j] = inputs@W_ih^T + b_ih + b_hh (f16 MFMA 16x16x32)
// ---------------------------------------------------------------------------
__global__ __launch_bounds__(256) void gemm_in(
    const float* __restrict__ A, const _Float16* __restrict__ W16,
    const float* __restrict__ b_ih, const float* __restrict__ b_hh,
    float* __restrict__ out) {
  __shared__ _Float16 As[64][264];
  const int t = threadIdx.x;
  const int m0 = blockIdx.x * 64;
  const int n0 = blockIdx.y * 256;
  {
    const int c4 = t & 63, r0 = t >> 6;
#pragma unroll
    for (int p = 0; p < 16; ++p) {
      const int row = r0 + 4 * p;
      float4 v = *(const float4*)(A + (size_t)(m0 + row) * EE + c4 * 4);
      f16x4 h;
      h[0] = (_Float16)v.x; h[1] = (_Float16)v.y;
      h[2] = (_Float16)v.z; h[3] = (_Float16)v.w;
      *(f16x4*)&As[row][c4 * 4] = h;
    }
  }
  __syncthreads();
  const int w = t >> 6, L = t & 63;
  const int lrow = L & 15, quad = L >> 4, lk = quad * 8;
  f32x4 acc[4][4] = {};
  const _Float16* Wbase = W16 + (size_t)(n0 + w * 64) * EE;
#pragma unroll
  for (int kc = 0; kc < 8; ++kc) {
    f16x8 a[4], bf[4];
#pragma unroll
    for (int mf = 0; mf < 4; ++mf)
      a[mf] = *(const f16x8*)&As[mf * 16 + lrow][kc * 32 + lk];
#pragma unroll
    for (int nf = 0; nf < 4; ++nf)
      bf[nf] = *(const f16x8*)(Wbase + (size_t)(nf * 16 + lrow) * EE + kc * 32 + lk);
#pragma unroll
    for (int mf = 0; mf < 4; ++mf)
#pragma unroll
      for (int nf = 0; nf < 4; ++nf)
        acc[mf][nf] = __builtin_amdgcn_mfma_f32_16x16x32_f16(a[mf], bf[nf], acc[mf][nf], 0, 0, 0);
  }
#pragma unroll
  for (int nf = 0; nf < 4; ++nf) {
    const int jj = n0 + w * 64 + nf * 16 + lrow;
    const float bias = b_ih[jj] + b_hh[jj];
#pragma unroll
    for (int mf = 0; mf < 4; ++mf) {
#pragma unroll
      for (int r = 0; r < 4; ++r) {
        const int m = m0 + mf * 16 + quad * 4 + r;
        out[(size_t)m * G4 + jj] = acc[mf][nf][r] + bias;
      }
    }
  }
}

// ---------------------------------------------------------------------------
// Kernel C: fused LSTM + softmax + CRF forward.  One block (256 thr = 4 waves)
// per batch, 1 wave/SIMD, big VGPR budget.  W_hh and exp(trans)^T preloaded as
// MFMA A-fragments in registers; h/E broadcast via 4 ds_read_b128 B-fragments
// per wave per step (all-cols-equal matvec trick).  Wave w owns unit-tiles
// {w, w+4}: all 4 gates of a unit land in one lane's accumulators.  Lane
// (quad,col) handles unit ju = 16w + 64*(col>>3) + quad*4 + (col&3), 2-fold
// redundant.  One barrier/step; CRF lags LSTM by one iteration (double-
// buffered h16/E16/redE/pre0).  Reductions via DPP (VALU pipe).
// ---------------------------------------------------------------------------
__global__ __launch_bounds__(256, 1) void lstm_crf(
    const float* __restrict__ precomp, const _Float16* __restrict__ Whh16,
    const _Float16* __restrict__ ETT, const float* __restrict__ trans,
    const int* __restrict__ labels, float* __restrict__ out_b) {
  const int b = blockIdx.x, t = threadIdx.x;
  const int w = t >> 6, L = t & 63;
  const int quad = L >> 4, col = L & 15;
  const int r4 = col & 3, sel = (col >> 3) & 1;
  const int ju = 16 * w + 64 * sel + quad * 4 + r4;  // owned unit
  const bool writer = ((col & 4) == 0);              // cols 0-3 and 8-11

  __shared__ __align__(16) _Float16 h16[2][HH];
  __shared__ __align__(16) _Float16 E16[2][HH];
  __shared__ __align__(16) float redE[2][4];
  __shared__ float pre0[2];
  __shared__ float fin[12];
  __shared__ int lab[TT];

  // ---- one-time A-fragment loads (stay in VGPRs for all 512 steps) --------
  f16x8 Al[4][2][4];  // [gate][unit-tile 0/1][kc]
#pragma unroll
  for (int g = 0; g < 4; ++g)
#pragma unroll
    for (int u = 0; u < 2; ++u) {
      const int row = g * 128 + u * 64 + 16 * w + col;  // A row-in-tile = col
#pragma unroll
      for (int kc = 0; kc < 4; ++kc)
        Al[g][u][kc] = *(const f16x8*)(Whh16 + row * HH + kc * 32 + quad * 8);
    }
  f16x8 Ac[2][4];  // CRF: A = exp(trans)^T rows = units
#pragma unroll
  for (int u = 0; u < 2; ++u) {
    const int row = u * 64 + 16 * w + col;
#pragma unroll
    for (int kc = 0; kc < 4; ++kc)
      Ac[u][kc] = *(const f16x8*)(ETT + row * HH + kc * 32 + quad * 8);
  }
  const float tr0 = trans[ju];
  const float tr127 = trans[127 * HH + ju];
  lab[t] = labels[b * TT + t];
  lab[t + 256] = labels[b * TT + t + 256];
  if (t < HH) {
    h16[0][t] = (_Float16)0.f; h16[1][t] = (_Float16)0.f;
    E16[0][t] = (_Float16)0.f; E16[1][t] = (_Float16)0.f;
  }
  if (t < 8) redE[t >> 2][t & 3] = 0.f;
  if (t < 2) pre0[t] = 0.f;

  float cst = 0.f, pre = 0.f, mused = 0.f, emit = 0.f, e_prev = 0.f;
  const float* pcb = precomp + (size_t)b * TT * G4;
  const int rowoff = 16 * w + quad * 4;
  float4 nxt[8];  // precomp prefetch, D/C-layout float4 (rows quad*4..+3)
#pragma unroll
  for (int g = 0; g < 4; ++g)
#pragma unroll
    for (int u = 0; u < 2; ++u)
      nxt[g * 2 + u] = *(const float4*)(pcb + g * 128 + u * 64 + rowoff);
  __syncthreads();

#pragma unroll 1
  for (int n = 0; n <= TT; ++n) {
    const _Float16* hb = &h16[(n + 1) & 1][0];  // h(n-1)
    const _Float16* eb = &E16[n & 1][0];        // E(n-2)
    f16x8 Bh[4], Be[4];
    if (n < TT) {
#pragma unroll
      for (int kc = 0; kc < 4; ++kc)
        Bh[kc] = *(const f16x8*)(hb + kc * 32 + quad * 8);
    }
    if (n > 0) {
#pragma unroll
      for (int kc = 0; kc < 4; ++kc)
        Be[kc] = *(const f16x8*)(eb + kc * 32 + quad * 8);
    }
    const float4 rE = *(const float4*)&redE[(n + 1) & 1][0];  // tot(n-1), 2x
    float Mnew = pre0[(n + 1) & 1];                           // pre(n-2)[0]
    const int labn = lab[(n > 0 ? n : 1) - 1];

    float e_cur = 0.f;
    if (n < TT) {
      f32x4 acc[8];
#pragma unroll
      for (int i = 0; i < 8; ++i) acc[i] = __builtin_bit_cast(f32x4, nxt[i]);
#pragma unroll
      for (int kc = 0; kc < 4; ++kc)
#pragma unroll
        for (int i = 0; i < 8; ++i)
          acc[i] = __builtin_amdgcn_mfma_f32_16x16x32_f16(
              Al[i >> 1][i & 1][kc], Bh[kc], acc[i], 0, 0, 0);
      // my unit's 4 gates (acc index g*2+sel, element r4 = D-row quad*4+r4)
      const float gi = sel ? sel4(acc[1], r4) : sel4(acc[0], r4);
      const float gf = sel ? sel4(acc[3], r4) : sel4(acc[2], r4);
      const float gg = sel ? sel4(acc[5], r4) : sel4(acc[4], r4);
      const float go = sel ? sel4(acc[7], r4) : sel4(acc[6], r4);
      cst = sigmoid_(gf) * cst + sigmoid_(gi) * tanh_(gg);
      const float hv = sigmoid_(go) * tanh_(cst);
      e_cur = __expf(hv);  // |hv|<1
      float ts = wave_sum63(e_cur);           // lane63: 2x wave-unit sum
      if (L == 63) redE[n & 1][w] = ts;
      if (writer) h16[n & 1][ju] = (_Float16)hv;
    }
    // prefetch next step's precomp (after acc consumed nxt)
    if (n + 1 < TT) {
      const float* p2 = pcb + (size_t)(n + 1) * G4;
#pragma unroll
      for (int g = 0; g < 4; ++g)
#pragma unroll
        for (int u = 0; u < 2; ++u)
          nxt[g * 2 + u] = *(const float4*)(p2 + g * 128 + u * 64 + rowoff);
    }
    if (n > 0) {
      f32x4 s0 = {0.f, 0.f, 0.f, 0.f}, s1 = {0.f, 0.f, 0.f, 0.f};
#pragma unroll
      for (int kc = 0; kc < 4; ++kc) {
        s0 = __builtin_amdgcn_mfma_f32_16x16x32_f16(Ac[0][kc], Be[kc], s0, 0, 0, 0);
        s1 = __builtin_amdgcn_mfma_f32_16x16x32_f16(Ac[1][kc], Be[kc], s1, 0, 0, 0);
      }
      const float S = sel ? sel4(s1, r4) : sel4(s0, r4);
      const float tot = rE.x + rE.y + rE.z + rE.w;  // 2x true total
      const float p = e_prev * 2.f * rcp_(tot);     // softmax prob of ju
      if (n == 1) { pre = p + tr0; Mnew = 0.f; }
      else pre = p + mused + __logf(S);
      if (t == 0) pre0[n & 1] = pre;  // t==0 owns unit 0
      if (writer) E16[(n + 1) & 1][ju] = (_Float16)__expf(pre - Mnew);
      mused = Mnew;
      if (writer && labn == ju) emit += p;
    }
    e_prev = e_cur;
    __syncthreads();
  }

  // ---- epilogue: Ps = LSE_j(pre + trans[127][j]); out_b = Ps - emit -------
  float v = pre + tr127;  // valid on all lanes (2x redundant per unit)
  float mx = v;
#pragma unroll
  for (int d = 1; d <= 32; d <<= 1) mx = fmaxf(mx, __shfl_xor(mx, d));
  if (L == 0) fin[w] = mx;
  __syncthreads();
  const float M2 = fmaxf(fmaxf(fin[0], fin[1]), fmaxf(fin[2], fin[3]));
  float ex = wave_sum63(__expf(v - M2));    // lane63: 2x wave sum
  float em = wave_sum63(writer ? emit : 0.f);
  if (L == 63) { fin[4 + w] = ex; fin[8 + w] = em; }
  __syncthreads();
  if (t == 0) {
    float S = 0.f, E = 0.f;
#pragma unroll
    for (int i = 0; i < 4; ++i) { S += fin[4 + i]; E += fin[8 + i]; }
    out_b[b] = (M2 + __logf(S * 0.5f)) - E;
  }
}

// ---------------------------------------------------------------------------
// Kernel D: d_out += out_b[b] - sum_t trans[l_t][l_{t+1}]   (one block per b)
// ---------------------------------------------------------------------------
__global__ __launch_bounds__(256) void finalize_kernel(
    const float* __restrict__ trans, const int* __restrict__ labels,
    const float* __restrict__ out_b, float* __restrict__ d_out) {
  const int b = blockIdx.x, t = threadIdx.x;
  float a = 0.f;
  for (int i = t; i < TT - 1; i += 256) {
    const int l0 = labels[b * TT + i];
    const int l1 = labels[b * TT + i + 1];
    a += trans[l0 * HH + l1];
  }
#pragma unroll
  for (int d = 1; d <= 32; d <<= 1) a += __shfl_xor(a, d);
  __shared__ float red[4];
  if ((t & 63) == 0) red[t >> 6] = a;
  __syncthreads();
  if (t == 0) {
    const float tr = red[0] + red[1] + red[2] + red[3];
    atomicAdd(d_out, out_b[b] - tr);
  }
}

// ---------------------------------------------------------------------------
extern "C" void kernel_launch(void* const* d_in, const int* in_sizes, int n_in,
                              void* d_out, int out_size, void* d_ws, size_t ws_size,
                              hipStream_t stream) {
  const float* inputs = (const float*)d_in[0];
  const int* labels = (const int*)d_in[1];
  const float* W_ih = (const float*)d_in[2];
  const float* W_hh = (const float*)d_in[3];
  const float* b_ih = (const float*)d_in[4];
  const float* b_hh = (const float*)d_in[5];
  const float* transition = (const float*)d_in[6];

  char* ws = (char*)d_ws;
  float* precomp = (float*)ws;                              // 64 MiB
  size_t off = 67108864;
  float* trans = (float*)(ws + off); off += 65536;          // 64 KiB
  _Float16* W16 = (_Float16*)(ws + off); off += 262144;     // 256 KiB
  _Float16* Whh16 = (_Float16*)(ws + off); off += 131072;   // 128 KiB
  _Float16* ETT = (_Float16*)(ws + off); off += 32768;      // 32 KiB
  float* out_b = (float*)(ws + off);

  prep_kernel<<<320, 128, 0, stream>>>(transition, W_ih, W_hh, trans, W16, Whh16);
  prep2_kernel<<<64, 256, 0, stream>>>(trans, ETT);
  gemm_in<<<dim3(512, 2), 256, 0, stream>>>(inputs, W16, b_ih, b_hh, precomp);
  lstm_crf<<<64, 256, 0, stream>>>(precomp, Whh16, ETT, trans, labels, out_b);
  (void)hipMemsetAsync(d_out, 0, sizeof(float), stream);
  finalize_kernel<<<64, 256, 0, stream>>>(trans, labels, out_b, (float*)d_out);
}